// Round 4
// baseline (371.429 us; speedup 1.0000x reference)
//
#include <hip/hip_runtime.h>
#include <cstdint>

typedef __bf16 bf16_t;
typedef __bf16 bf16x8 __attribute__((ext_vector_type(8)));
typedef float  f32x4  __attribute__((ext_vector_type(4)));

// Workspace layout
#define XPAD_ELEMS (32UL*58*58*128)      // padded NHWC bf16 input
#define WPERM_OFF  (XPAD_ELEMS*2)        // bytes (27,557,888 — 256B aligned)
#define WPERM_ELEMS (256UL*9*128)
#define WS_NEEDED  (WPERM_OFF + WPERM_ELEMS*2)

// async global->LDS, 16B per lane; lds dest is wave-uniform base + lane*16
__device__ __forceinline__ void async16(const bf16_t* g, bf16_t* l) {
  __builtin_amdgcn_global_load_lds(
      (const __attribute__((address_space(1))) void*)g,
      (__attribute__((address_space(3))) void*)l, 16, 0, 0);
}

// ------- transpose+convert x: NCHW f32 -> padded NHWC bf16 (32,58,58,128) -------
__global__ __launch_bounds__(256) void k_xform(const float* __restrict__ x, bf16_t* __restrict__ Xp) {
  const int b = blockIdx.x;
  const int n = b / 58, hp = b % 58;
  bf16_t* drow = Xp + ((size_t)n * 58 + hp) * 58 * 128;
  const int t = threadIdx.x;
  uint4 z; z.x = z.y = z.z = z.w = 0;
  if (hp == 0 || hp == 57) {             // full border row
    uint4* p = (uint4*)drow;
    for (int i = t; i < 928; i += 256) p[i] = z;
    return;
  }
  if (t < 32) {                           // border pixels w=0 and w=57
    uint4* p0 = (uint4*)drow;
    uint4* p1 = (uint4*)(drow + 57 * 128);
    if (t < 16) p0[t] = z; else p1[t - 16] = z;
  }
  const int h = hp - 1;
  const float* src = x + (size_t)n * 401408 + h * 56;   // + c*3136 + w
  __shared__ float lds[128 * 57];
  for (int i = t; i < 7168; i += 256) {   // 128 c * 56 w
    int c = i / 56;
    int w = i - c * 56;
    lds[c * 57 + w] = src[(size_t)c * 3136 + w];
  }
  __syncthreads();
  bf16_t* dst = drow + 128;               // w starts at 1
  for (int i = t; i < 3584; i += 256) {   // pairs of channels
    int cp = i & 63, w = i >> 6;
    int c0 = cp * 2;
    unsigned short u0 = __builtin_bit_cast(unsigned short, (bf16_t)lds[c0 * 57 + w]);
    unsigned short u1 = __builtin_bit_cast(unsigned short, (bf16_t)lds[(c0 + 1) * 57 + w]);
    *(unsigned int*)(dst + (size_t)w * 128 + c0) = (unsigned)u0 | ((unsigned)u1 << 16);
  }
}

// ------- weight permute: OIHW (256,128,3,3) f32 -> (256, 9, 128) bf16 -------
__global__ void k_wperm(const float* __restrict__ wt, bf16_t* __restrict__ Wp) {
  int i = blockIdx.x * 256 + threadIdx.x;
  if (i >= 294912) return;
  int k = i / 1152;
  int rem = i - k * 1152;
  int rs = rem >> 7;
  int c = rem & 127;
  Wp[i] = (bf16_t)wt[k * 1152 + c * 9 + rs];
}

// ---------------- naive fp32 fallback (only if ws too small) ----------------
__global__ void k_naive(const float* __restrict__ x, const float* __restrict__ wt,
                        const float* __restrict__ bs, float* __restrict__ out) {
  int idx = blockIdx.x * 256 + threadIdx.x;
  if (idx >= 25690112) return;
  int w = idx % 56; int tmp = idx / 56;
  int h = tmp % 56; tmp /= 56;
  int k = tmp % 256; int n = tmp / 256;
  float acc = bs[k];
  for (int c = 0; c < 128; ++c)
    for (int r = 0; r < 3; ++r) {
      int hy = h + r - 1; if ((unsigned)hy >= 56u) continue;
      for (int s = 0; s < 3; ++s) {
        int wx = w + s - 1; if ((unsigned)wx >= 56u) continue;
        acc += x[((size_t)(n * 128 + c) * 56 + hy) * 56 + wx] *
               wt[((size_t)(k * 128 + c) * 3 + r) * 3 + s];
      }
    }
  out[idx] = acc;
}

// ---------------- main implicit-GEMM MFMA conv (m97 structure, 64B staging) ----
// A = Wperm (256 x 1152), B = im2col(Xpad) (1152 x 100352), reduce order ck = rs*128 + c.
// K-step t (BK=32): rs = t>>2, c0 = (t&3)*32. Per-step element offset into padded NHWC row:
#define BROFF(t) (((((t) >> 2) / 3) * 58 + (((t) >> 2) % 3)) * 128 + ((t) & 3) * 32)

// LDS tiles: [row/pixel][slot][8 bf16]; physical slot s of row r holds logical
// 8-ch chunk g = s ^ ((r>>1)&3). Staging: 4 lanes per row read one contiguous
// 64B line (chunks permuted to match slots). Fragment ds_read_b128 keeps the
// optimal 8-lanes-per-slot bank profile (conflict-free, verified r3: 0 conflicts).
__global__ __launch_bounds__(256, 5) void k_conv(const bf16_t* __restrict__ Xp,
                                                 const bf16_t* __restrict__ Wp,
                                                 const float* __restrict__ bias,
                                                 float* __restrict__ out) {
  __shared__ bf16_t Alds[2][128][4][8];   // 2 x 8 KB
  __shared__ bf16_t Blds[2][128][4][8];   // 2 x 8 KB
  const int tid = threadIdx.x;
  const int lane = tid & 63;
  const int wv = tid >> 6;

  // XCD pairing: both m-tiles of a p-tile keep the same (blockIdx % 8) -> same XCD.
  const int x = (int)blockIdx.x;          // grid = 1568 = 16 * 98
  const int chunk = x >> 4, within = x & 15;
  const int m0 = (within >> 3) * 128;
  const int p0 = (chunk * 8 + (within & 7)) * 128;
  const int wr = wv >> 1, wc = wv & 1;

  // --- staging mapping: group ga = wv*2+j covers rows/pixels [ga*16, ga*16+16)
  //     lane -> row ga*16 + (lane>>2), slot s = lane&3, global chunk g = s ^ ((row>>1)&3)
  const int sr0 = wv * 32 + (lane >> 2);       // j=0 row within tile
  const int sr1 = sr0 + 16;                    // j=1
  const int sg0 = (lane & 3) ^ ((sr0 >> 1) & 3);
  const int sg1 = (lane & 3) ^ ((sr1 >> 1) & 3);

  const bf16_t* wA0 = Wp + (size_t)(m0 + sr0) * 1152 + sg0 * 8;
  const bf16_t* wA1 = Wp + (size_t)(m0 + sr1) * 1152 + sg1 * 8;

  int p_lo = p0 + sr0, p_hi = p0 + sr1;
  int ni_lo = p_lo / 3136, ni_hi = p_hi / 3136;
  int hw_lo = p_lo - ni_lo * 3136, hw_hi = p_hi - ni_hi * 3136;
  int hh_lo = hw_lo / 56, hh_hi = hw_hi / 56;
  int ww_lo = hw_lo - hh_lo * 56, ww_hi = hw_hi - hh_hi * 56;
  const bf16_t* xb0 = Xp + (((size_t)ni_lo * 58 + hh_lo) * 58 + ww_lo) * 128 + sg0 * 8;
  const bf16_t* xb1 = Xp + (((size_t)ni_hi * 58 + hh_hi) * 58 + ww_hi) * 128 + sg1 * 8;

#define STAGE(buf, tt) do {                                       \
    async16(wA0 + (tt) * 32,   &Alds[buf][wv * 32][0][0]);        \
    async16(wA1 + (tt) * 32,   &Alds[buf][wv * 32 + 16][0][0]);   \
    async16(xb0 + BROFF(tt),   &Blds[buf][wv * 32][0][0]);        \
    async16(xb1 + BROFF(tt),   &Blds[buf][wv * 32 + 16][0][0]);   \
  } while (0)

  // --- fragment read addressing (slot const per lane: mi*16>>1 ≡ 0 mod 4)
  const int fr = lane & 15, fg = lane >> 4;
  const int ra = wr * 64 + fr;
  const int pa = wc * 64 + fr;
  const int slA = fg ^ ((ra >> 1) & 3);
  const int slB = fg ^ ((pa >> 1) & 3);

  f32x4 acc[4][4] = {};

  STAGE(0, 0);
  __syncthreads();          // compiler drains vmcnt before the barrier

#pragma unroll
  for (int t = 0; t < 36; ++t) {
    const int cur = t & 1;
    const int nxt = cur ^ 1;
    if (t + 1 < 36) STAGE(nxt, t + 1);   // issue next tile early; completes by barrier
    bf16x8 afr[4], bfr[4];
#pragma unroll
    for (int mi = 0; mi < 4; ++mi)
      afr[mi] = *(const bf16x8*)&Alds[cur][ra + mi * 16][slA][0];
#pragma unroll
    for (int ni = 0; ni < 4; ++ni)
      bfr[ni] = *(const bf16x8*)&Blds[cur][pa + ni * 16][slB][0];
#pragma unroll
    for (int mi = 0; mi < 4; ++mi)
#pragma unroll
      for (int ni = 0; ni < 4; ++ni)
        acc[mi][ni] = __builtin_amdgcn_mfma_f32_16x16x32_bf16(afr[mi], bfr[ni], acc[mi][ni], 0, 0, 0);
    __syncthreads();
  }
#undef STAGE

  // epilogue: D reg j of lane -> row=(l>>4)*4+j, col=l&15 (verified layout)
  float bv[4][4];
#pragma unroll
  for (int mi = 0; mi < 4; ++mi)
#pragma unroll
    for (int j = 0; j < 4; ++j)
      bv[mi][j] = bias[m0 + wr * 64 + mi * 16 + (lane >> 4) * 4 + j];

#pragma unroll
  for (int ni = 0; ni < 4; ++ni) {
    int p = p0 + wc * 64 + ni * 16 + (lane & 15);
    int nim = p / 3136;
    int hw2 = p - nim * 3136;
    float* ob = out + (size_t)nim * 802816 + hw2;
#pragma unroll
    for (int mi = 0; mi < 4; ++mi) {
      int rowb = m0 + wr * 64 + mi * 16 + (lane >> 4) * 4;
#pragma unroll
      for (int j = 0; j < 4; ++j)
        ob[(size_t)(rowb + j) * 3136] = acc[mi][ni][j] + bv[mi][j];
    }
  }
}

extern "C" void kernel_launch(void* const* d_in, const int* in_sizes, int n_in,
                              void* d_out, int out_size, void* d_ws, size_t ws_size,
                              hipStream_t stream) {
  const float* x  = (const float*)d_in[0];
  const float* wt = (const float*)d_in[1];
  const float* bs = (const float*)d_in[2];
  float* out = (float*)d_out;

  if (ws_size < WS_NEEDED) {     // safety net: direct fp32 conv
    k_naive<<<(25690112 + 255) / 256, 256, 0, stream>>>(x, wt, bs, out);
    return;
  }

  bf16_t* Xp = (bf16_t*)d_ws;
  bf16_t* Wp = (bf16_t*)((char*)d_ws + WPERM_OFF);

  k_xform<<<1856, 256, 0, stream>>>(x, Xp);                 // 32*58 padded rows
  k_wperm<<<1152, 256, 0, stream>>>(wt, Wp);                // 294912 / 256
  k_conv <<<1568, 256, 0, stream>>>(Xp, Wp, bs, out);       // 16 * 98 (XCD-paired)
}

// Round 5
// 212.854 us; speedup vs baseline: 1.7450x; 1.7450x over previous
//
#include <hip/hip_runtime.h>
#include <cstdint>

typedef __bf16 bf16_t;
typedef __bf16 bf16x8 __attribute__((ext_vector_type(8)));
typedef float  f32x4  __attribute__((ext_vector_type(4)));

// Workspace layout
#define XPAD_ELEMS (32UL*58*58*128)      // padded NHWC bf16 input
#define WPERM_OFF  (XPAD_ELEMS*2)        // bytes (27,557,888 — 256B aligned)
#define WPERM_ELEMS (256UL*9*128)
#define WS_NEEDED  (WPERM_OFF + WPERM_ELEMS*2)

// async global->LDS, 16B per lane; lds dest is wave-uniform base + lane*16
__device__ __forceinline__ void async16(const bf16_t* g, bf16_t* l) {
  __builtin_amdgcn_global_load_lds(
      (const __attribute__((address_space(1))) void*)g,
      (__attribute__((address_space(3))) void*)l, 16, 0, 0);
}

// ------- transpose+convert x: NCHW f32 -> padded NHWC bf16 (32,58,58,128) -------
__global__ __launch_bounds__(256) void k_xform(const float* __restrict__ x, bf16_t* __restrict__ Xp) {
  const int b = blockIdx.x;
  const int n = b / 58, hp = b % 58;
  bf16_t* drow = Xp + ((size_t)n * 58 + hp) * 58 * 128;
  const int t = threadIdx.x;
  uint4 z; z.x = z.y = z.z = z.w = 0;
  if (hp == 0 || hp == 57) {             // full border row
    uint4* p = (uint4*)drow;
    for (int i = t; i < 928; i += 256) p[i] = z;
    return;
  }
  if (t < 32) {                           // border pixels w=0 and w=57
    uint4* p0 = (uint4*)drow;
    uint4* p1 = (uint4*)(drow + 57 * 128);
    if (t < 16) p0[t] = z; else p1[t - 16] = z;
  }
  const int h = hp - 1;
  const float* src = x + (size_t)n * 401408 + h * 56;   // + c*3136 + w
  __shared__ float lds[128 * 57];
  for (int i = t; i < 7168; i += 256) {   // 128 c * 56 w
    int c = i / 56;
    int w = i - c * 56;
    lds[c * 57 + w] = src[(size_t)c * 3136 + w];
  }
  __syncthreads();
  bf16_t* dst = drow + 128;               // w starts at 1
  for (int i = t; i < 3584; i += 256) {   // pairs of channels
    int cp = i & 63, w = i >> 6;
    int c0 = cp * 2;
    unsigned short u0 = __builtin_bit_cast(unsigned short, (bf16_t)lds[c0 * 57 + w]);
    unsigned short u1 = __builtin_bit_cast(unsigned short, (bf16_t)lds[(c0 + 1) * 57 + w]);
    *(unsigned int*)(dst + (size_t)w * 128 + c0) = (unsigned)u0 | ((unsigned)u1 << 16);
  }
}

// ------- weight permute: OIHW (256,128,3,3) f32 -> (256, 9, 128) bf16 -------
__global__ void k_wperm(const float* __restrict__ wt, bf16_t* __restrict__ Wp) {
  int i = blockIdx.x * 256 + threadIdx.x;
  if (i >= 294912) return;
  int k = i / 1152;
  int rem = i - k * 1152;
  int rs = rem >> 7;
  int c = rem & 127;
  Wp[i] = (bf16_t)wt[k * 1152 + c * 9 + rs];
}

// ---------------- naive fp32 fallback (only if ws too small) ----------------
__global__ void k_naive(const float* __restrict__ x, const float* __restrict__ wt,
                        const float* __restrict__ bs, float* __restrict__ out) {
  int idx = blockIdx.x * 256 + threadIdx.x;
  if (idx >= 25690112) return;
  int w = idx % 56; int tmp = idx / 56;
  int h = tmp % 56; tmp /= 56;
  int k = tmp % 256; int n = tmp / 256;
  float acc = bs[k];
  for (int c = 0; c < 128; ++c)
    for (int r = 0; r < 3; ++r) {
      int hy = h + r - 1; if ((unsigned)hy >= 56u) continue;
      for (int s = 0; s < 3; ++s) {
        int wx = w + s - 1; if ((unsigned)wx >= 56u) continue;
        acc += x[((size_t)(n * 128 + c) * 56 + hy) * 56 + wx] *
               wt[((size_t)(k * 128 + c) * 3 + r) * 3 + s];
      }
    }
  out[idx] = acc;
}

// ---------------- main implicit-GEMM MFMA conv ----------------
// r3 structure (verbatim staging/grid/LDS layout) + T3/T4: 4-deep LDS ring,
// stage-ahead 2, raw s_barrier + counted vmcnt(8) — loads stay in flight
// across barriers so L2/HBM miss latency overlaps 2 K-steps of MFMA work.
// A = Wperm (256 x 1152), B = im2col(Xpad) (1152 x 100352), ck = rs*128 + c.
// K-step t (BK=32): rs = t>>2, c0 = (t&3)*32.
#define BROFF(t) (((((t) >> 2) / 3) * 58 + (((t) >> 2) % 3)) * 128 + ((t) & 3) * 32)

__global__ __launch_bounds__(256, 2) void k_conv(const bf16_t* __restrict__ Xp,
                                                 const bf16_t* __restrict__ Wp,
                                                 const float* __restrict__ bias,
                                                 float* __restrict__ out) {
  // [buf][kc][row][8]: gload_lds writes linear (base + lane*16); conflict-free reads.
  __shared__ bf16_t Alds[4][4][128][8];   // 32 KB
  __shared__ bf16_t Blds[4][4][128][8];   // 32 KB
  const int tid = threadIdx.x;
  const int lane = tid & 63;
  const int wv = tid >> 6;
  const int m0 = ((int)blockIdx.x & 1) * 128;
  const int p0 = ((int)blockIdx.x >> 1) * 128;
  const int wr = wv >> 1, wc = wv & 1;

  // --- staging source pointers (per lane). Wave wv stages kc=wv for both A and B.
  const bf16_t* wA0 = Wp + (size_t)(m0 + lane) * 1152 + wv * 8;
  const bf16_t* wA1 = Wp + (size_t)(m0 + 64 + lane) * 1152 + wv * 8;
  int p_lo = p0 + lane, p_hi = p0 + 64 + lane;
  int ni_lo = p_lo / 3136, ni_hi = p_hi / 3136;
  int hw_lo = p_lo - ni_lo * 3136, hw_hi = p_hi - ni_hi * 3136;
  int hh_lo = hw_lo / 56, hh_hi = hw_hi / 56;
  int ww_lo = hw_lo - hh_lo * 56, ww_hi = hw_hi - hh_hi * 56;
  const bf16_t* xb0 = Xp + (((size_t)ni_lo * 58 + hh_lo) * 58 + ww_lo) * 128 + wv * 8;
  const bf16_t* xb1 = Xp + (((size_t)ni_hi * 58 + hh_hi) * 58 + ww_hi) * 128 + wv * 8;

#define STAGE(buf, tt) do {                                   \
    async16(wA0 + (tt) * 32, &Alds[buf][wv][0][0]);           \
    async16(wA1 + (tt) * 32, &Alds[buf][wv][64][0]);          \
    async16(xb0 + BROFF(tt), &Blds[buf][wv][0][0]);           \
    async16(xb1 + BROFF(tt), &Blds[buf][wv][64][0]);          \
  } while (0)

  f32x4 acc[4][4] = {};

  STAGE(0, 0);          // 4 outstanding
  STAGE(1, 1);          // 8 outstanding

#pragma unroll
  for (int t = 0; t < 36; ++t) {
    const int cur = t & 3;
    if (t + 2 < 36) STAGE((t + 2) & 3, t + 2);   // 12 outstanding (steady state)
    // wait own stage(t) done (leave newest 2 stages in flight), then sync all waves
    if (t < 34)       asm volatile("s_waitcnt vmcnt(8)" ::: "memory");
    else if (t == 34) asm volatile("s_waitcnt vmcnt(4)" ::: "memory");
    else              asm volatile("s_waitcnt vmcnt(0)" ::: "memory");
    __builtin_amdgcn_s_barrier();
    asm volatile("" ::: "memory");               // no LDS-read hoist above barrier
    __builtin_amdgcn_sched_barrier(0);

    bf16x8 afr[4], bfr[4];
#pragma unroll
    for (int mi = 0; mi < 4; ++mi)
      afr[mi] = *(const bf16x8*)&Alds[cur][lane >> 4][wr * 64 + mi * 16 + (lane & 15)][0];
#pragma unroll
    for (int ni = 0; ni < 4; ++ni)
      bfr[ni] = *(const bf16x8*)&Blds[cur][lane >> 4][wc * 64 + ni * 16 + (lane & 15)][0];
#pragma unroll
    for (int mi = 0; mi < 4; ++mi)
#pragma unroll
      for (int ni = 0; ni < 4; ++ni)
        acc[mi][ni] = __builtin_amdgcn_mfma_f32_16x16x32_bf16(afr[mi], bfr[ni], acc[mi][ni], 0, 0, 0);
    // no trailing barrier: next iter writes buf (t+3)&3, never the buf being read
  }
#undef STAGE

  // epilogue: D reg j of lane -> row=(l>>4)*4+j, col=l&15 (verified layout)
  float bv[4][4];
#pragma unroll
  for (int mi = 0; mi < 4; ++mi)
#pragma unroll
    for (int j = 0; j < 4; ++j)
      bv[mi][j] = bias[m0 + wr * 64 + mi * 16 + (lane >> 4) * 4 + j];

#pragma unroll
  for (int ni = 0; ni < 4; ++ni) {
    int p = p0 + wc * 64 + ni * 16 + (lane & 15);
    int nim = p / 3136;
    int hw2 = p - nim * 3136;
    float* ob = out + (size_t)nim * 802816 + hw2;
#pragma unroll
    for (int mi = 0; mi < 4; ++mi) {
      int rowb = m0 + wr * 64 + mi * 16 + (lane >> 4) * 4;
#pragma unroll
      for (int j = 0; j < 4; ++j)
        ob[(size_t)(rowb + j) * 3136] = acc[mi][ni][j] + bv[mi][j];
    }
  }
}

extern "C" void kernel_launch(void* const* d_in, const int* in_sizes, int n_in,
                              void* d_out, int out_size, void* d_ws, size_t ws_size,
                              hipStream_t stream) {
  const float* x  = (const float*)d_in[0];
  const float* wt = (const float*)d_in[1];
  const float* bs = (const float*)d_in[2];
  float* out = (float*)d_out;

  if (ws_size < WS_NEEDED) {     // safety net: direct fp32 conv
    k_naive<<<(25690112 + 255) / 256, 256, 0, stream>>>(x, wt, bs, out);
    return;
  }

  bf16_t* Xp = (bf16_t*)d_ws;
  bf16_t* Wp = (bf16_t*)((char*)d_ws + WPERM_OFF);

  k_xform<<<1856, 256, 0, stream>>>(x, Xp);                 // 32*58 padded rows
  k_wperm<<<1152, 256, 0, stream>>>(wt, Wp);                // 294912 / 256
  k_conv <<<1568, 256, 0, stream>>>(Xp, Wp, bs, out);       // 2 m-tiles * 784 p-tiles
}

// Round 6
// 121.300 us; speedup vs baseline: 3.0621x; 1.7548x over previous
//
#include <hip/hip_runtime.h>
#include <cstdint>

typedef __bf16 bf16_t;
typedef __bf16 bf16x8 __attribute__((ext_vector_type(8)));
typedef float  f32x4  __attribute__((ext_vector_type(4)));

// Workspace layout
#define XPAD_ELEMS (32UL*58*58*128)      // padded NHWC bf16 input
#define WPERM_OFF  (XPAD_ELEMS*2)        // bytes
#define WPERM_ELEMS (256UL*9*128)        // 294912
#define WS_NEEDED  (WPERM_OFF + WPERM_ELEMS*2)

// async global->LDS, 16B per lane; lds dest is wave-uniform base + lane*16
__device__ __forceinline__ void async16(const bf16_t* g, const bf16_t* l) {
  __builtin_amdgcn_global_load_lds(
      (const __attribute__((address_space(1))) void*)g,
      (__attribute__((address_space(3))) void*)l, 16, 0, 0);
}

// ------- transpose+convert x: NCHW f32 -> padded NHWC bf16 (32,58,58,128) -------
__global__ __launch_bounds__(256) void k_xform(const float* __restrict__ x, bf16_t* __restrict__ Xp) {
  const int b = blockIdx.x;
  const int n = b / 58, hp = b % 58;
  bf16_t* drow = Xp + ((size_t)n * 58 + hp) * 58 * 128;
  const int t = threadIdx.x;
  uint4 z; z.x = z.y = z.z = z.w = 0;
  if (hp == 0 || hp == 57) {             // full border row
    uint4* p = (uint4*)drow;
    for (int i = t; i < 928; i += 256) p[i] = z;
    return;
  }
  if (t < 32) {                           // border pixels w=0 and w=57
    uint4* p0 = (uint4*)drow;
    uint4* p1 = (uint4*)(drow + 57 * 128);
    if (t < 16) p0[t] = z; else p1[t - 16] = z;
  }
  const int h = hp - 1;
  const float* src = x + (size_t)n * 401408 + h * 56;   // + c*3136 + w
  __shared__ float lds[128 * 57];
  for (int i = t; i < 7168; i += 256) {   // 128 c * 56 w
    int c = i / 56;
    int w = i - c * 56;
    lds[c * 57 + w] = src[(size_t)c * 3136 + w];
  }
  __syncthreads();
  bf16_t* dst = drow + 128;               // w starts at 1
  for (int i = t; i < 3584; i += 256) {   // pairs of channels
    int cp = i & 63, w = i >> 6;
    int c0 = cp * 2;
    unsigned short u0 = __builtin_bit_cast(unsigned short, (bf16_t)lds[c0 * 57 + w]);
    unsigned short u1 = __builtin_bit_cast(unsigned short, (bf16_t)lds[(c0 + 1) * 57 + w]);
    *(unsigned int*)(dst + (size_t)w * 128 + c0) = (unsigned)u0 | ((unsigned)u1 << 16);
  }
}

// ------- weight prepack: OIHW f32 -> Wpk, the exact per-K-step LDS image -------
// Wpk flat index i = ((t*2 + mh)*512 + flat16)*8 + e, where t = K-step (rs*4+ci),
// mh = m-half, flat16 = kc*128 + row (kc in 0..3, row in 0..127), e in 0..7.
// Value = wt[o=mh*128+row][c = ci*32 + kc*8 + e][tap rs] (cross-correlation order).
__global__ void k_wperm(const float* __restrict__ wt, bf16_t* __restrict__ Wp) {
  int i = blockIdx.x * 256 + threadIdx.x;
  if (i >= 294912) return;
  int t      = i >> 13;         // /8192
  int r1     = i & 8191;
  int mh     = r1 >> 12;
  int r2     = r1 & 4095;
  int flat16 = r2 >> 3;
  int e      = r2 & 7;
  int kc  = flat16 >> 7;
  int row = flat16 & 127;
  int o  = mh * 128 + row;
  int ci = t & 3, rs = t >> 2;
  int c  = ci * 32 + kc * 8 + e;
  Wp[i] = (bf16_t)wt[o * 1152 + c * 9 + rs];
}

// ---------------- naive fp32 fallback (only if ws too small) ----------------
__global__ void k_naive(const float* __restrict__ x, const float* __restrict__ wt,
                        const float* __restrict__ bs, float* __restrict__ out) {
  int idx = blockIdx.x * 256 + threadIdx.x;
  if (idx >= 25690112) return;
  int w = idx % 56; int tmp = idx / 56;
  int h = tmp % 56; tmp /= 56;
  int k = tmp % 256; int n = tmp / 256;
  float acc = bs[k];
  for (int c = 0; c < 128; ++c)
    for (int r = 0; r < 3; ++r) {
      int hy = h + r - 1; if ((unsigned)hy >= 56u) continue;
      for (int s = 0; s < 3; ++s) {
        int wx = w + s - 1; if ((unsigned)wx >= 56u) continue;
        acc += x[((size_t)(n * 128 + c) * 56 + hy) * 56 + wx] *
               wt[((size_t)(k * 128 + c) * 3 + r) * 3 + s];
      }
    }
  out[idx] = acc;
}

// ---------------- main conv: strip-resident B, dbuf A, MFMA ----------------
// Block = 128 out-ch (mh) x 112 pixels (2 output rows of one image).
// B: 4-row padded strip (4x58 pixels x 128ch bf16 = 59392B) staged ONCE into LDS,
//    chunk-XOR-swizzled (phys chunk = logical ^ (w&7)) so im2col ds_read_b128 is 2-way.
// A: per-K-step 8KB slice of prepacked Wpk, double-buffered, fully-sequential gload_lds.
// 4 waves; wave wv owns 32 out-ch; acc[2][7] frags of 16x16; 14 MFMA/step.
__global__ __launch_bounds__(256, 2) void k_conv(const bf16_t* __restrict__ Xp,
                                                 const bf16_t* __restrict__ Wpk,
                                                 const float* __restrict__ bias,
                                                 float* __restrict__ out) {
  __shared__ bf16_t strip[3712 * 8];      // 59392 B: [h'4][w'58][chunk16][8ch]
  __shared__ bf16_t Alds[2][4096];        // 2 x 8 KB:  [kc4][row128][8]
  const int tid = threadIdx.x, lane = tid & 63, wv = tid >> 6;
  const int bid = (int)blockIdx.x;
  const int mh  = bid & 1;
  const int sid = bid >> 1;               // 0..895
  const int n   = sid / 28;
  const int h0  = (sid - n * 28) * 2;     // padded strip rows h0..h0+3

  // ---- strip staging: 14 full rounds + half round (waves 0,1) ----
  const bf16_t* xrow = Xp + ((size_t)n * 58 + h0) * 58 * 128;
#pragma unroll
  for (int r = 0; r < 14; ++r) {
    int slot = r * 256 + tid;
    int pix = slot >> 4, cp = slot & 15;
    int hp = pix / 58, wp = pix - hp * 58;
    int cl = cp ^ (wp & 7);               // fetch logical chunk into phys slot
    async16(xrow + ((size_t)(hp * 58 + wp)) * 128 + cl * 8,
            strip + (r * 256 + wv * 64) * 8);
  }
  if (tid < 128) {                        // waves 0,1 fully active — no divergence
    int slot = 3584 + tid;
    int pix = slot >> 4, cp = slot & 15;
    int hp = pix / 58, wp = pix - hp * 58;
    int cl = cp ^ (wp & 7);
    async16(xrow + ((size_t)(hp * 58 + wp)) * 128 + cl * 8,
            strip + (3584 + wv * 64) * 8);
  }

  // ---- A staging (Wpk is laid out exactly as the LDS image) ----
  const bf16_t* wsrc = Wpk + (size_t)mh * 4096;   // + t*8192 + flat16*8
#define STAGE_A(buf, tt) do {                                              \
    async16(wsrc + (size_t)(tt) * 8192 + (0 * 256 + tid) * 8,              \
            &Alds[buf][(0 * 256 + wv * 64) * 8]);                          \
    async16(wsrc + (size_t)(tt) * 8192 + (1 * 256 + tid) * 8,              \
            &Alds[buf][(1 * 256 + wv * 64) * 8]);                          \
  } while (0)

  STAGE_A(0, 0);
  __syncthreads();          // drains vmcnt: strip + A(0) all landed

  // ---- per-lane fragment geometry ----
  const int fr = lane & 15, fg = lane >> 4;
  int pixb[7], owm[7];
#pragma unroll
  for (int ni = 0; ni < 7; ++ni) {
    int pq = ni * 16 + fr;                // tile pixel 0..111
    int oh = (pq >= 56) ? 1 : 0;
    int ow = pq - oh * 56;
    pixb[ni] = oh * 58 + ow;
    owm[ni]  = ow;
  }

  f32x4 acc[2][7] = {};

#pragma unroll
  for (int t = 0; t < 36; ++t) {
    const int cur = t & 1, nxt = cur ^ 1;
    if (t + 1 < 36) STAGE_A(nxt, t + 1);  // L2-hit sequential; lands by barrier
    const int rs = t >> 2, ci = t & 3;
    const int r = rs / 3, s = rs - r * 3;

    bf16x8 afr[2], bfr[7];
#pragma unroll
    for (int mi = 0; mi < 2; ++mi)
      afr[mi] = *(const bf16x8*)&Alds[cur][(fg * 128 + wv * 32 + mi * 16 + fr) * 8];
#pragma unroll
    for (int ni = 0; ni < 7; ++ni) {
      int cph = (ci * 4 + fg) ^ ((owm[ni] + s) & 7);
      bfr[ni] = *(const bf16x8*)&strip[((pixb[ni] + r * 58 + s) * 16 + cph) * 8];
    }
#pragma unroll
    for (int mi = 0; mi < 2; ++mi)
#pragma unroll
      for (int ni = 0; ni < 7; ++ni)
        acc[mi][ni] = __builtin_amdgcn_mfma_f32_16x16x32_bf16(afr[mi], bfr[ni], acc[mi][ni], 0, 0, 0);
    __syncthreads();                      // protects Alds[nxt] WAR across waves
  }
#undef STAGE_A

  // ---- epilogue: D reg j -> row=(lane>>4)*4+j, col=lane&15 (verified layout) ----
  const int mbase = mh * 128 + wv * 32;
  float bv[2][4];
#pragma unroll
  for (int mi = 0; mi < 2; ++mi)
#pragma unroll
    for (int j = 0; j < 4; ++j)
      bv[mi][j] = bias[mbase + mi * 16 + fg * 4 + j];

#pragma unroll
  for (int ni = 0; ni < 7; ++ni) {
    int pq = ni * 16 + fr;
    int oh = (pq >= 56) ? 1 : 0;
    int ow = pq - oh * 56;
    int h = h0 + oh;                      // output row (h0 is also the top padded row)
    float* ob = out + (size_t)n * 802816 + h * 56 + ow;
#pragma unroll
    for (int mi = 0; mi < 2; ++mi) {
      int kb = mbase + mi * 16 + fg * 4;
#pragma unroll
      for (int j = 0; j < 4; ++j)
        ob[(size_t)(kb + j) * 3136] = acc[mi][ni][j] + bv[mi][j];
    }
  }
}

extern "C" void kernel_launch(void* const* d_in, const int* in_sizes, int n_in,
                              void* d_out, int out_size, void* d_ws, size_t ws_size,
                              hipStream_t stream) {
  const float* x  = (const float*)d_in[0];
  const float* wt = (const float*)d_in[1];
  const float* bs = (const float*)d_in[2];
  float* out = (float*)d_out;

  if (ws_size < WS_NEEDED) {     // safety net: direct fp32 conv
    k_naive<<<(25690112 + 255) / 256, 256, 0, stream>>>(x, wt, bs, out);
    return;
  }

  bf16_t* Xp  = (bf16_t*)d_ws;
  bf16_t* Wpk = (bf16_t*)((char*)d_ws + WPERM_OFF);

  k_xform<<<1856, 256, 0, stream>>>(x, Xp);                 // 32*58 padded rows
  k_wperm<<<1152, 256, 0, stream>>>(wt, Wpk);               // 294912 / 256
  k_conv <<<1792, 256, 0, stream>>>(Xp, Wpk, bs, out);      // 32 img * 28 strips * 2 mh
}

// Round 7
// 105.126 us; speedup vs baseline: 3.5332x; 1.1539x over previous
//
#include <hip/hip_runtime.h>
#include <cstdint>

typedef __bf16 bf16_t;
typedef __bf16 bf16x8 __attribute__((ext_vector_type(8)));
typedef float  f32x4  __attribute__((ext_vector_type(4)));

// Workspace layout
#define XPAD_ELEMS (32UL*58*58*128)      // padded NHWC bf16 input
#define WPERM_OFF  (XPAD_ELEMS*2)        // bytes
#define WPERM_ELEMS (256UL*9*128)        // 294912
#define WS_NEEDED  (WPERM_OFF + WPERM_ELEMS*2)

// async global->LDS, 16B per lane; lds dest is wave-uniform base + lane*16
__device__ __forceinline__ void async16(const bf16_t* g, const bf16_t* l) {
  __builtin_amdgcn_global_load_lds(
      (const __attribute__((address_space(1))) void*)g,
      (__attribute__((address_space(3))) void*)l, 16, 0, 0);
}

// ------- transpose+convert x: NCHW f32 -> padded NHWC bf16 (32,58,58,128) -------
__global__ __launch_bounds__(256) void k_xform(const float* __restrict__ x, bf16_t* __restrict__ Xp) {
  const int b = blockIdx.x;
  const int n = b / 58, hp = b % 58;
  bf16_t* drow = Xp + ((size_t)n * 58 + hp) * 58 * 128;
  const int t = threadIdx.x;
  uint4 z; z.x = z.y = z.z = z.w = 0;
  if (hp == 0 || hp == 57) {             // full border row
    uint4* p = (uint4*)drow;
    for (int i = t; i < 928; i += 256) p[i] = z;
    return;
  }
  if (t < 32) {                           // border pixels w=0 and w=57
    uint4* p0 = (uint4*)drow;
    uint4* p1 = (uint4*)(drow + 57 * 128);
    if (t < 16) p0[t] = z; else p1[t - 16] = z;
  }
  const int h = hp - 1;
  const float* src = x + (size_t)n * 401408 + h * 56;   // + c*3136 + w
  __shared__ float lds[128 * 57];
  for (int i = t; i < 7168; i += 256) {   // 128 c * 56 w
    int c = i / 56;
    int w = i - c * 56;
    lds[c * 57 + w] = src[(size_t)c * 3136 + w];
  }
  __syncthreads();
  bf16_t* dst = drow + 128;               // w starts at 1
  for (int i = t; i < 3584; i += 256) {   // pairs of channels
    int cp = i & 63, w = i >> 6;
    int c0 = cp * 2;
    unsigned short u0 = __builtin_bit_cast(unsigned short, (bf16_t)lds[c0 * 57 + w]);
    unsigned short u1 = __builtin_bit_cast(unsigned short, (bf16_t)lds[(c0 + 1) * 57 + w]);
    *(unsigned int*)(dst + (size_t)w * 128 + c0) = (unsigned)u0 | ((unsigned)u1 << 16);
  }
}

// ------- weight prepack: OIHW f32 -> Wpk, per-K-step register-fragment image -------
// Wpk flat index i = ((t*2 + mh)*512 + flat16)*8 + e, t = K-step (rs*4+ci),
// mh = out-ch half, flat16 = kc*128 + row, e in 0..7.
// Value = wt[o=mh*128+row][c = ci*32 + kc*8 + e][tap rs].
__global__ void k_wperm(const float* __restrict__ wt, bf16_t* __restrict__ Wp) {
  int i = blockIdx.x * 256 + threadIdx.x;
  if (i >= 294912) return;
  int t      = i >> 13;         // /8192
  int r1     = i & 8191;
  int mh     = r1 >> 12;
  int r2     = r1 & 4095;
  int flat16 = r2 >> 3;
  int e      = r2 & 7;
  int kc  = flat16 >> 7;
  int row = flat16 & 127;
  int o  = mh * 128 + row;
  int ci = t & 3, rs = t >> 2;
  int c  = ci * 32 + kc * 8 + e;
  Wp[i] = (bf16_t)wt[o * 1152 + c * 9 + rs];
}

// ---------------- naive fp32 fallback (only if ws too small) ----------------
__global__ void k_naive(const float* __restrict__ x, const float* __restrict__ wt,
                        const float* __restrict__ bs, float* __restrict__ out) {
  int idx = blockIdx.x * 256 + threadIdx.x;
  if (idx >= 25690112) return;
  int w = idx % 56; int tmp = idx / 56;
  int h = tmp % 56; tmp /= 56;
  int k = tmp % 256; int n = tmp / 256;
  float acc = bs[k];
  for (int c = 0; c < 128; ++c)
    for (int r = 0; r < 3; ++r) {
      int hy = h + r - 1; if ((unsigned)hy >= 56u) continue;
      for (int s = 0; s < 3; ++s) {
        int wx = w + s - 1; if ((unsigned)wx >= 56u) continue;
        acc += x[((size_t)(n * 128 + c) * 56 + hy) * 56 + wx] *
               wt[((size_t)(k * 128 + c) * 3 + r) * 3 + s];
      }
    }
  out[idx] = acc;
}

// ---------------- main conv: barrier-free K-loop, reg-resident A ----------------
// Block = 8 waves (512 thr) = ALL 256 out-ch x 112 pixels (2 output rows).
// B: 4-row padded strip (59392B) staged ONCE into LDS (chunk-XOR swizzle, r6 pattern).
// A: per-wave private 32 out-ch; 2 fragments/step loaded from L2-resident Wpk into
//    registers with distance-2 prefetch. K-loop has NO barriers — waves free-run.
__global__ __launch_bounds__(512, 4) void k_conv(const bf16_t* __restrict__ Xp,
                                                 const bf16_t* __restrict__ Wpk,
                                                 const float* __restrict__ bias,
                                                 float* __restrict__ out) {
  __shared__ bf16_t strip[3712 * 8];      // 59392 B: [pix 4*58][chunk16][8ch]
  const int tid = threadIdx.x, lane = tid & 63, wv = tid >> 6;
  const int sid = (int)blockIdx.x;        // 0..895
  const int n   = sid / 28;
  const int h0  = (sid - n * 28) * 2;     // padded strip rows h0..h0+3

  // ---- strip staging: 7 full rounds + 128 slots (waves 0,1) ----
  const bf16_t* xrow = Xp + ((size_t)n * 58 + h0) * 58 * 128;
#pragma unroll
  for (int r = 0; r < 7; ++r) {
    int slot = r * 512 + tid;
    int pix = slot >> 4, cp = slot & 15;
    int hp = pix / 58, wp = pix - hp * 58;
    int cl = cp ^ (wp & 7);               // fetch logical chunk into phys slot
    async16(xrow + ((size_t)(hp * 58 + wp)) * 128 + cl * 8,
            strip + (r * 512 + wv * 64) * 8);
  }
  if (tid < 128) {
    int slot = 3584 + tid;
    int pix = slot >> 4, cp = slot & 15;
    int hp = pix / 58, wp = pix - hp * 58;
    int cl = cp ^ (wp & 7);
    async16(xrow + ((size_t)(hp * 58 + wp)) * 128 + cl * 8,
            strip + (3584 + wv * 64) * 8);
  }

  // ---- per-lane geometry ----
  const int fr = lane & 15, fg = lane >> 4;
  int pixb[7];
#pragma unroll
  for (int ni = 0; ni < 7; ++ni) {
    int pq = ni * 16 + fr;                // tile pixel 0..111
    int oh = (pq >= 56) ? 1 : 0;
    pixb[ni] = pq + 2 * oh;               // strip pixel = oh*58 + ow
  }

  // ---- A fragment source: wave-private rows, contiguous per 16-lane group ----
  const bf16_t* wsrc = Wpk + (size_t)(wv >> 2) * 4096 +
                       (fg * 128 + (wv & 3) * 32 + fr) * 8;
  bf16x8 areg[2][2];
  areg[0][0] = *(const bf16x8*)(wsrc);                 // t=0
  areg[0][1] = *(const bf16x8*)(wsrc + 128);
  areg[1][0] = *(const bf16x8*)(wsrc + 8192);          // t=1
  areg[1][1] = *(const bf16x8*)(wsrc + 8192 + 128);

  __syncthreads();           // strip landed (vmcnt drain) — ONLY barrier

  f32x4 acc[2][7] = {};

#pragma unroll
  for (int t = 0; t < 36; ++t) {
    const int pb = t & 1;                 // static under full unroll
    const int rs = t >> 2, ci = t & 3;
    const int r = rs / 3, s = rs - r * 3;
    const int cph = (ci * 4 + fg) ^ ((fr + s) & 7);    // ni-independent
    const int base = ((r * 58 + s) * 16 + cph) * 8;

    bf16x8 bfr[7];
#pragma unroll
    for (int ni = 0; ni < 7; ++ni)
      bfr[ni] = *(const bf16x8*)&strip[pixb[ni] * 128 + base];
#pragma unroll
    for (int mi = 0; mi < 2; ++mi)
#pragma unroll
      for (int ni = 0; ni < 7; ++ni)
        acc[mi][ni] = __builtin_amdgcn_mfma_f32_16x16x32_bf16(areg[pb][mi], bfr[ni], acc[mi][ni], 0, 0, 0);
    if (t + 2 < 36) {                     // distance-2 prefetch into just-freed slot
      areg[pb][0] = *(const bf16x8*)(wsrc + (size_t)(t + 2) * 8192);
      areg[pb][1] = *(const bf16x8*)(wsrc + (size_t)(t + 2) * 8192 + 128);
    }
  }

  // ---- epilogue: D reg j -> row=(lane>>4)*4+j, col=lane&15 ----
  const int mbase = wv * 32;
  float bv[2][4];
#pragma unroll
  for (int mi = 0; mi < 2; ++mi)
#pragma unroll
    for (int j = 0; j < 4; ++j)
      bv[mi][j] = bias[mbase + mi * 16 + fg * 4 + j];

#pragma unroll
  for (int ni = 0; ni < 7; ++ni) {
    int pq = ni * 16 + fr;
    int oh = (pq >= 56) ? 1 : 0;
    int ow = pq - oh * 56;
    int h = h0 + oh;
    float* ob = out + (size_t)n * 802816 + h * 56 + ow;
#pragma unroll
    for (int mi = 0; mi < 2; ++mi) {
      int kb = mbase + mi * 16 + fg * 4;
#pragma unroll
      for (int j = 0; j < 4; ++j)
        ob[(size_t)(kb + j) * 3136] = acc[mi][ni][j] + bv[mi][j];
    }
  }
}

extern "C" void kernel_launch(void* const* d_in, const int* in_sizes, int n_in,
                              void* d_out, int out_size, void* d_ws, size_t ws_size,
                              hipStream_t stream) {
  const float* x  = (const float*)d_in[0];
  const float* wt = (const float*)d_in[1];
  const float* bs = (const float*)d_in[2];
  float* out = (float*)d_out;

  if (ws_size < WS_NEEDED) {     // safety net: direct fp32 conv
    k_naive<<<(25690112 + 255) / 256, 256, 0, stream>>>(x, wt, bs, out);
    return;
  }

  bf16_t* Xp  = (bf16_t*)d_ws;
  bf16_t* Wpk = (bf16_t*)((char*)d_ws + WPERM_OFF);

  k_xform<<<1856, 256, 0, stream>>>(x, Xp);                 // 32*58 padded rows
  k_wperm<<<1152, 256, 0, stream>>>(wt, Wpk);               // 294912 / 256
  k_conv <<<896, 512, 0, stream>>>(Xp, Wpk, bs, out);       // 32 img * 28 strips
}

// Round 8
// 79.193 us; speedup vs baseline: 4.6902x; 1.3275x over previous
//
#include <hip/hip_runtime.h>
#include <cstdint>

typedef __bf16 bf16_t;
typedef __bf16 bf16x8 __attribute__((ext_vector_type(8)));
typedef float  f32x4  __attribute__((ext_vector_type(4)));

// Workspace layout
#define XPAD_ELEMS (32UL*58*58*128)      // padded NHWC bf16 input
#define WPERM_OFF  (XPAD_ELEMS*2)        // bytes
#define WPERM_ELEMS (256UL*9*128)        // 294912
#define WS_NEEDED  (WPERM_OFF + WPERM_ELEMS*2)

// async global->LDS, 16B per lane; lds dest is wave-uniform base + lane*16
__device__ __forceinline__ void async16(const bf16_t* g, const bf16_t* l) {
  __builtin_amdgcn_global_load_lds(
      (const __attribute__((address_space(1))) void*)g,
      (__attribute__((address_space(3))) void*)l, 16, 0, 0);
}

// ------- transpose+convert x: NCHW f32 -> padded NHWC bf16 (32,58,58,128) -------
__global__ __launch_bounds__(256) void k_xform(const float* __restrict__ x, bf16_t* __restrict__ Xp) {
  const int b = blockIdx.x;
  const int n = b / 58, hp = b % 58;
  bf16_t* drow = Xp + ((size_t)n * 58 + hp) * 58 * 128;
  const int t = threadIdx.x;
  uint4 z; z.x = z.y = z.z = z.w = 0;
  if (hp == 0 || hp == 57) {             // full border row
    uint4* p = (uint4*)drow;
    for (int i = t; i < 928; i += 256) p[i] = z;
    return;
  }
  if (t < 32) {                           // border pixels w=0 and w=57
    uint4* p0 = (uint4*)drow;
    uint4* p1 = (uint4*)(drow + 57 * 128);
    if (t < 16) p0[t] = z; else p1[t - 16] = z;
  }
  const int h = hp - 1;
  const float* src = x + (size_t)n * 401408 + h * 56;   // + c*3136 + w
  __shared__ float lds[128 * 57];
  for (int i = t; i < 7168; i += 256) {   // 128 c * 56 w
    int c = i / 56;
    int w = i - c * 56;
    lds[c * 57 + w] = src[(size_t)c * 3136 + w];
  }
  __syncthreads();
  bf16_t* dst = drow + 128;               // w starts at 1
  for (int i = t; i < 3584; i += 256) {   // pairs of channels
    int cp = i & 63, w = i >> 6;
    int c0 = cp * 2;
    unsigned short u0 = __builtin_bit_cast(unsigned short, (bf16_t)lds[c0 * 57 + w]);
    unsigned short u1 = __builtin_bit_cast(unsigned short, (bf16_t)lds[(c0 + 1) * 57 + w]);
    *(unsigned int*)(dst + (size_t)w * 128 + c0) = (unsigned)u0 | ((unsigned)u1 << 16);
  }
}

// ------- weight prepack: OIHW f32 -> Wpk[t][kc][o][e] register-fragment image -------
// i = t*8192 + kc*2048 + o*8 + e ; value = wt[o][c = ci*32 + kc*8 + e][tap rs],
// with ci = t&3, rs = t>>2. A-frag for lane(fr,fg): o = wv*64+mi*16+fr, kc = fg.
__global__ void k_wperm(const float* __restrict__ wt, bf16_t* __restrict__ Wp) {
  int i = blockIdx.x * 256 + threadIdx.x;
  if (i >= 294912) return;
  int e  = i & 7;
  int o  = (i >> 3) & 255;
  int kc = (i >> 11) & 3;
  int t  = i >> 13;
  int ci = t & 3, rs = t >> 2;
  int c  = ci * 32 + kc * 8 + e;
  Wp[i] = (bf16_t)wt[o * 1152 + c * 9 + rs];
}

// ---------------- naive fp32 fallback (only if ws too small) ----------------
__global__ void k_naive(const float* __restrict__ x, const float* __restrict__ wt,
                        const float* __restrict__ bs, float* __restrict__ out) {
  int idx = blockIdx.x * 256 + threadIdx.x;
  if (idx >= 25690112) return;
  int w = idx % 56; int tmp = idx / 56;
  int h = tmp % 56; tmp /= 56;
  int k = tmp % 256; int n = tmp / 256;
  float acc = bs[k];
  for (int c = 0; c < 128; ++c)
    for (int r = 0; r < 3; ++r) {
      int hy = h + r - 1; if ((unsigned)hy >= 56u) continue;
      for (int s = 0; s < 3; ++s) {
        int wx = w + s - 1; if ((unsigned)wx >= 56u) continue;
        acc += x[((size_t)(n * 128 + c) * 56 + hy) * 56 + wx] *
               wt[((size_t)(k * 128 + c) * 3 + r) * 3 + s];
      }
    }
  out[idx] = acc;
}

// ---------------- main conv: barrier-free K-loop, M_wave=64 ----------------
// Block = 4 waves (256 thr); wave owns 64 out-ch x 112 pixels (2 output rows).
// B: 4-row padded strip (59392B) staged ONCE into LDS (chunk-XOR swizzle).
//    7 ds_read_b128/step/wave now feed 28 MFMA (ratio 4 — was 2 at M_wave=32).
// A: reg-resident, distance-2 prefetch from L2-resident Wpk (contiguous 256B runs).
// K-loop has NO barriers — waves free-run.
__global__ __launch_bounds__(256, 2) void k_conv(const bf16_t* __restrict__ Xp,
                                                 const bf16_t* __restrict__ Wpk,
                                                 const float* __restrict__ bias,
                                                 float* __restrict__ out) {
  __shared__ bf16_t strip[3712 * 8];      // 59392 B: [pix 4*58][chunk16][8ch]
  const int tid = threadIdx.x, lane = tid & 63, wv = tid >> 6;   // wv 0..3
  const int sid = (int)blockIdx.x;        // 0..895
  const int n   = sid / 28;
  const int h0  = (sid - n * 28) * 2;     // padded strip rows h0..h0+3

  // ---- strip staging: 14 full rounds + 128 slots (waves 0,1) ----
  const bf16_t* xrow = Xp + ((size_t)n * 58 + h0) * 58 * 128;
#pragma unroll
  for (int r = 0; r < 14; ++r) {
    int slot = r * 256 + tid;
    int pix = slot >> 4, cp = slot & 15;
    int hp = pix / 58, wp = pix - hp * 58;
    int cl = cp ^ (wp & 7);               // fetch logical chunk into phys slot
    async16(xrow + ((size_t)(hp * 58 + wp)) * 128 + cl * 8,
            strip + (r * 256 + wv * 64) * 8);
  }
  if (tid < 128) {                        // waves 0,1 fully active
    int slot = 3584 + tid;
    int pix = slot >> 4, cp = slot & 15;
    int hp = pix / 58, wp = pix - hp * 58;
    int cl = cp ^ (wp & 7);
    async16(xrow + ((size_t)(hp * 58 + wp)) * 128 + cl * 8,
            strip + (3584 + wv * 64) * 8);
  }

  // ---- per-lane geometry ----
  const int fr = lane & 15, fg = lane >> 4;
  int pixb[7];
#pragma unroll
  for (int ni = 0; ni < 7; ++ni) {
    int pq = ni * 16 + fr;                // tile pixel 0..111
    int oh = (pq >= 56) ? 1 : 0;
    pixb[ni] = pq + 2 * oh;               // strip pixel = oh*58 + ow
  }

  // ---- A fragment source: wave-private 64 rows, contiguous per 16-lane group ----
  const bf16_t* wsrc = Wpk + fg * 2048 + (wv * 64 + fr) * 8;  // + t*8192 + mi*128
  bf16x8 areg[2][4];
#pragma unroll
  for (int mi = 0; mi < 4; ++mi) {
    areg[0][mi] = *(const bf16x8*)(wsrc + mi * 128);          // t=0
    areg[1][mi] = *(const bf16x8*)(wsrc + 8192 + mi * 128);   // t=1
  }

  __syncthreads();           // strip landed (vmcnt drain) — ONLY barrier

  f32x4 acc[4][7] = {};

#pragma unroll
  for (int t = 0; t < 36; ++t) {
    const int pb = t & 1;                 // static under full unroll
    const int rs = t >> 2, ci = t & 3;
    const int r = rs / 3, s = rs - r * 3;
    const int cph = (ci * 4 + fg) ^ ((fr + s) & 7);    // ni-independent
    const int base = ((r * 58 + s) * 16 + cph) * 8;

    bf16x8 bfr[7];
#pragma unroll
    for (int ni = 0; ni < 7; ++ni)
      bfr[ni] = *(const bf16x8*)&strip[pixb[ni] * 128 + base];
#pragma unroll
    for (int mi = 0; mi < 4; ++mi)
#pragma unroll
      for (int ni = 0; ni < 7; ++ni)
        acc[mi][ni] = __builtin_amdgcn_mfma_f32_16x16x32_bf16(areg[pb][mi], bfr[ni], acc[mi][ni], 0, 0, 0);
    if (t + 2 < 36) {                     // distance-2 prefetch into just-freed slots
#pragma unroll
      for (int mi = 0; mi < 4; ++mi)
        areg[pb][mi] = *(const bf16x8*)(wsrc + (size_t)(t + 2) * 8192 + mi * 128);
    }
  }

  // ---- epilogue: D reg j -> row=(lane>>4)*4+j, col=lane&15 ----
  const int mbase = wv * 64;
  float bv[4][4];
#pragma unroll
  for (int mi = 0; mi < 4; ++mi)
#pragma unroll
    for (int j = 0; j < 4; ++j)
      bv[mi][j] = bias[mbase + mi * 16 + fg * 4 + j];

#pragma unroll
  for (int ni = 0; ni < 7; ++ni) {
    int pq = ni * 16 + fr;
    int oh = (pq >= 56) ? 1 : 0;
    int ow = pq - oh * 56;
    int h = h0 + oh;
    float* ob = out + (size_t)n * 802816 + h * 56 + ow;
#pragma unroll
    for (int mi = 0; mi < 4; ++mi) {
      int kb = mbase + mi * 16 + fg * 4;
#pragma unroll
      for (int j = 0; j < 4; ++j)
        ob[(size_t)(kb + j) * 3136] = acc[mi][ni][j] + bv[mi][j];
    }
  }
}

extern "C" void kernel_launch(void* const* d_in, const int* in_sizes, int n_in,
                              void* d_out, int out_size, void* d_ws, size_t ws_size,
                              hipStream_t stream) {
  const float* x  = (const float*)d_in[0];
  const float* wt = (const float*)d_in[1];
  const float* bs = (const float*)d_in[2];
  float* out = (float*)d_out;

  if (ws_size < WS_NEEDED) {     // safety net: direct fp32 conv
    k_naive<<<(25690112 + 255) / 256, 256, 0, stream>>>(x, wt, bs, out);
    return;
  }

  bf16_t* Xp  = (bf16_t*)d_ws;
  bf16_t* Wpk = (bf16_t*)((char*)d_ws + WPERM_OFF);

  k_xform<<<1856, 256, 0, stream>>>(x, Xp);                 // 32*58 padded rows
  k_wperm<<<1152, 256, 0, stream>>>(wt, Wpk);               // 294912 / 256
  k_conv <<<896, 256, 0, stream>>>(Xp, Wpk, bs, out);       // 32 img * 28 strips
}

// Round 9
// 78.630 us; speedup vs baseline: 4.7238x; 1.0072x over previous
//
#include <hip/hip_runtime.h>
#include <cstdint>

typedef __bf16 bf16_t;
typedef __bf16 bf16x8 __attribute__((ext_vector_type(8)));
typedef float  f32x4  __attribute__((ext_vector_type(4)));

// Workspace layout
#define XPAD_ELEMS (32UL*58*58*128)      // padded NHWC bf16 input
#define WPERM_OFF  (XPAD_ELEMS*2)        // bytes
#define WPERM_ELEMS (256UL*9*128)        // 294912
#define WS_NEEDED  (WPERM_OFF + WPERM_ELEMS*2)

// async global->LDS, 16B per lane; lds dest is wave-uniform base + lane*16
__device__ __forceinline__ void async16(const bf16_t* g, const bf16_t* l) {
  __builtin_amdgcn_global_load_lds(
      (const __attribute__((address_space(1))) void*)g,
      (__attribute__((address_space(3))) void*)l, 16, 0, 0);
}

// ------- transpose+convert x: NCHW f32 -> padded NHWC bf16 (32,58,58,128) -------
__global__ __launch_bounds__(256) void k_xform(const float* __restrict__ x, bf16_t* __restrict__ Xp) {
  const int b = blockIdx.x;
  const int n = b / 58, hp = b % 58;
  bf16_t* drow = Xp + ((size_t)n * 58 + hp) * 58 * 128;
  const int t = threadIdx.x;
  uint4 z; z.x = z.y = z.z = z.w = 0;
  if (hp == 0 || hp == 57) {             // full border row
    uint4* p = (uint4*)drow;
    for (int i = t; i < 928; i += 256) p[i] = z;
    return;
  }
  if (t < 32) {                           // border pixels w=0 and w=57
    uint4* p0 = (uint4*)drow;
    uint4* p1 = (uint4*)(drow + 57 * 128);
    if (t < 16) p0[t] = z; else p1[t - 16] = z;
  }
  const int h = hp - 1;
  const float* src = x + (size_t)n * 401408 + h * 56;   // + c*3136 + w
  __shared__ float lds[128 * 57];
  for (int i = t; i < 7168; i += 256) {   // 128 c * 56 w
    int c = i / 56;
    int w = i - c * 56;
    lds[c * 57 + w] = src[(size_t)c * 3136 + w];
  }
  __syncthreads();
  bf16_t* dst = drow + 128;               // w starts at 1
  for (int i = t; i < 3584; i += 256) {   // pairs of channels
    int cp = i & 63, w = i >> 6;
    int c0 = cp * 2;
    unsigned short u0 = __builtin_bit_cast(unsigned short, (bf16_t)lds[c0 * 57 + w]);
    unsigned short u1 = __builtin_bit_cast(unsigned short, (bf16_t)lds[(c0 + 1) * 57 + w]);
    *(unsigned int*)(dst + (size_t)w * 128 + c0) = (unsigned)u0 | ((unsigned)u1 << 16);
  }
}

// ------- weight prepack: OIHW f32 -> Wpk[t][kc][o][e] register-fragment image -------
// i = t*8192 + kc*2048 + o*8 + e ; value = wt[o][c = ci*32 + kc*8 + e][tap rs],
// with ci = t&3, rs = t>>2. A-frag for lane(fr,fg): o = wv*64+mi*16+fr, kc = fg.
__global__ void k_wperm(const float* __restrict__ wt, bf16_t* __restrict__ Wp) {
  int i = blockIdx.x * 256 + threadIdx.x;
  if (i >= 294912) return;
  int e  = i & 7;
  int o  = (i >> 3) & 255;
  int kc = (i >> 11) & 3;
  int t  = i >> 13;
  int ci = t & 3, rs = t >> 2;
  int c  = ci * 32 + kc * 8 + e;
  Wp[i] = (bf16_t)wt[o * 1152 + c * 9 + rs];
}

// ---------------- naive fp32 fallback (only if ws too small) ----------------
__global__ void k_naive(const float* __restrict__ x, const float* __restrict__ wt,
                        const float* __restrict__ bs, float* __restrict__ out) {
  int idx = blockIdx.x * 256 + threadIdx.x;
  if (idx >= 25690112) return;
  int w = idx % 56; int tmp = idx / 56;
  int h = tmp % 56; tmp /= 56;
  int k = tmp % 256; int n = tmp / 256;
  float acc = bs[k];
  for (int c = 0; c < 128; ++c)
    for (int r = 0; r < 3; ++r) {
      int hy = h + r - 1; if ((unsigned)hy >= 56u) continue;
      for (int s = 0; s < 3; ++s) {
        int wx = w + s - 1; if ((unsigned)wx >= 56u) continue;
        acc += x[((size_t)(n * 128 + c) * 56 + hy) * 56 + wx] *
               wt[((size_t)(k * 128 + c) * 3 + r) * 3 + s];
      }
    }
  out[idx] = acc;
}

// ---------------- main conv: barrier-free K-loop, M_wave=64, pipelined B ----------
// Block = 4 waves (256 thr); wave owns 64 out-ch x 112 pixels (2 output rows).
// B: 4-row padded strip (59392B) staged ONCE into LDS (chunk-XOR swizzle);
//    per-step 7 ds_read_b128 DOUBLE-BUFFERED distance-1 so they retire under
//    the previous step's 28 MFMAs (latency off the critical path).
// A: reg-resident, distance-2 prefetch from L2-resident Wpk (contiguous 256B runs).
// K-loop has NO barriers — waves free-run; s_setprio(1) wraps the MFMA cluster.
__global__ __launch_bounds__(256, 2) void k_conv(const bf16_t* __restrict__ Xp,
                                                 const bf16_t* __restrict__ Wpk,
                                                 const float* __restrict__ bias,
                                                 float* __restrict__ out) {
  __shared__ bf16_t strip[3712 * 8];      // 59392 B: [pix 4*58][chunk16][8ch]
  const int tid = threadIdx.x, lane = tid & 63, wv = tid >> 6;   // wv 0..3
  const int sid = (int)blockIdx.x;        // 0..895
  const int n   = sid / 28;
  const int h0  = (sid - n * 28) * 2;     // padded strip rows h0..h0+3

  // ---- strip staging: 14 full rounds + 128 slots (waves 0,1) ----
  const bf16_t* xrow = Xp + ((size_t)n * 58 + h0) * 58 * 128;
#pragma unroll
  for (int r = 0; r < 14; ++r) {
    int slot = r * 256 + tid;
    int pix = slot >> 4, cp = slot & 15;
    int hp = pix / 58, wp = pix - hp * 58;
    int cl = cp ^ (wp & 7);               // fetch logical chunk into phys slot
    async16(xrow + ((size_t)(hp * 58 + wp)) * 128 + cl * 8,
            strip + (r * 256 + wv * 64) * 8);
  }
  if (tid < 128) {                        // waves 0,1 fully active
    int slot = 3584 + tid;
    int pix = slot >> 4, cp = slot & 15;
    int hp = pix / 58, wp = pix - hp * 58;
    int cl = cp ^ (wp & 7);
    async16(xrow + ((size_t)(hp * 58 + wp)) * 128 + cl * 8,
            strip + (3584 + wv * 64) * 8);
  }

  // ---- per-lane geometry ----
  const int fr = lane & 15, fg = lane >> 4;
  int pixoff[7];
#pragma unroll
  for (int ni = 0; ni < 7; ++ni) {
    int pq = ni * 16 + fr;                // tile pixel 0..111
    int oh = (pq >= 56) ? 1 : 0;
    pixoff[ni] = (pq + 2 * oh) * 128;     // strip element offset of pixel
  }

  // ---- A fragment source: wave-private 64 rows, contiguous per 16-lane group ----
  const bf16_t* wsrc = Wpk + fg * 2048 + (wv * 64 + fr) * 8;  // + t*8192 + mi*128
  bf16x8 areg[2][4];
#pragma unroll
  for (int mi = 0; mi < 4; ++mi) {
    areg[0][mi] = *(const bf16x8*)(wsrc + mi * 128);          // t=0
    areg[1][mi] = *(const bf16x8*)(wsrc + 8192 + mi * 128);   // t=1
  }

  // B-fragment base for step t (compile-time r,s,ci under full unroll):
  //   base(t) = ((r*58+s)*16 + cph)*8, cph = (ci*4+fg)^((fr+s)&7)
#define BBASE(t) ((((((t) >> 2) / 3) * 58 + ((t) >> 2) % 3) * 16 +                 \
                   ((((t) & 3) * 4 + fg) ^ ((fr + ((t) >> 2) % 3) & 7))) * 8)

  __syncthreads();           // strip landed (vmcnt drain) — ONLY barrier

  f32x4 acc[4][7] = {};
  bf16x8 bcur[7], bnxt[7];
#pragma unroll
  for (int ni = 0; ni < 7; ++ni)
    bcur[ni] = *(const bf16x8*)&strip[pixoff[ni] + BBASE(0)];

#pragma unroll
  for (int t = 0; t < 36; ++t) {
    const int pb = t & 1;                 // static under full unroll
    // prefetch next step's B fragments FIRST — retire under this step's MFMAs
    if (t + 1 < 36) {
      const int nb = BBASE(t + 1);
#pragma unroll
      for (int ni = 0; ni < 7; ++ni)
        bnxt[ni] = *(const bf16x8*)&strip[pixoff[ni] + nb];
    }
    __builtin_amdgcn_s_setprio(1);
#pragma unroll
    for (int mi = 0; mi < 4; ++mi)
#pragma unroll
      for (int ni = 0; ni < 7; ++ni)
        acc[mi][ni] = __builtin_amdgcn_mfma_f32_16x16x32_bf16(areg[pb][mi], bcur[ni], acc[mi][ni], 0, 0, 0);
    __builtin_amdgcn_s_setprio(0);
    if (t + 2 < 36) {                     // distance-2 A prefetch into freed slots
#pragma unroll
      for (int mi = 0; mi < 4; ++mi)
        areg[pb][mi] = *(const bf16x8*)(wsrc + (size_t)(t + 2) * 8192 + mi * 128);
    }
#pragma unroll
    for (int ni = 0; ni < 7; ++ni)        // SSA-renamed under unroll, no copies
      bcur[ni] = bnxt[ni];
  }
#undef BBASE

  // ---- epilogue: D reg j -> row=(lane>>4)*4+j, col=lane&15 ----
  const int mbase = wv * 64;
  float bv[4][4];
#pragma unroll
  for (int mi = 0; mi < 4; ++mi)
#pragma unroll
    for (int j = 0; j < 4; ++j)
      bv[mi][j] = bias[mbase + mi * 16 + fg * 4 + j];

#pragma unroll
  for (int ni = 0; ni < 7; ++ni) {
    int pq = ni * 16 + fr;
    int oh = (pq >= 56) ? 1 : 0;
    int ow = pq - oh * 56;
    int h = h0 + oh;
    float* ob = out + (size_t)n * 802816 + h * 56 + ow;
#pragma unroll
    for (int mi = 0; mi < 4; ++mi) {
      int kb = mbase + mi * 16 + fg * 4;
#pragma unroll
      for (int j = 0; j < 4; ++j)
        ob[(size_t)(kb + j) * 3136] = acc[mi][ni][j] + bv[mi][j];
    }
  }
}

extern "C" void kernel_launch(void* const* d_in, const int* in_sizes, int n_in,
                              void* d_out, int out_size, void* d_ws, size_t ws_size,
                              hipStream_t stream) {
  const float* x  = (const float*)d_in[0];
  const float* wt = (const float*)d_in[1];
  const float* bs = (const float*)d_in[2];
  float* out = (float*)d_out;

  if (ws_size < WS_NEEDED) {     // safety net: direct fp32 conv
    k_naive<<<(25690112 + 255) / 256, 256, 0, stream>>>(x, wt, bs, out);
    return;
  }

  bf16_t* Xp  = (bf16_t*)d_ws;
  bf16_t* Wpk = (bf16_t*)((char*)d_ws + WPERM_OFF);

  k_xform<<<1856, 256, 0, stream>>>(x, Xp);                 // 32*58 padded rows
  k_wperm<<<1152, 256, 0, stream>>>(wt, Wpk);               // 294912 / 256
  k_conv <<<896, 256, 0, stream>>>(Xp, Wpk, bs, out);       // 32 img * 28 strips
}